// Round 4
// baseline (4383.770 us; speedup 1.0000x reference)
//
#include <hip/hip_runtime.h>
#include <hip/hip_cooperative_groups.h>

namespace cg = cooperative_groups;

#define BB 32
#define TT 40
#define TS 39
#define VV 8000
#define EE 50
#define HH 2048

typedef short s16x8 __attribute__((ext_vector_type(8)));
typedef float f32x4 __attribute__((ext_vector_type(4)));

__device__ __forceinline__ float sigmf(float x) { return 1.0f / (1.0f + __expf(-x)); }
__device__ __forceinline__ float tanhf_fast(float x) { return 2.0f / (1.0f + __expf(-2.0f * x)) - 1.0f; }

__device__ __forceinline__ unsigned short f2bf(float x) {
    union { float f; unsigned u; } v; v.f = x;
    unsigned r = v.u + 0x7FFF + ((v.u >> 16) & 1);   // RNE
    return (unsigned short)(r >> 16);
}

// ---------------------------------------------------------------------------
// fp32 -> bf16 weight conversion, 4 elems/thread
// ---------------------------------------------------------------------------
__global__ void convert_kernel(const float* __restrict__ src,
                               unsigned short* __restrict__ dst, int n4) {
    int i = blockIdx.x * 256 + threadIdx.x;
    if (i < n4) {
        float4 v = ((const float4*)src)[i];
        ushort4 o;
        o.x = f2bf(v.x); o.y = f2bf(v.y); o.z = f2bf(v.z); o.w = f2bf(v.w);
        ((ushort4*)dst)[i] = o;
    }
}

// ---------------------------------------------------------------------------
// Phase A: xw[t][b][j] = emb[captions[b][t]] . Wih[j][:] + bih[j] + bhh[j]
// ---------------------------------------------------------------------------
__global__ void embed_proj_kernel(const int* __restrict__ caps,
                                  const float* __restrict__ emb,
                                  const float* __restrict__ Wih,
                                  const float* __restrict__ bih,
                                  const float* __restrict__ bhh,
                                  float* __restrict__ xw) {
    __shared__ float elds[BB][EE];
    int t = blockIdx.y;
    int j = blockIdx.x * 256 + threadIdx.x;
    for (int idx = threadIdx.x; idx < BB * EE; idx += 256) {
        int bl = idx / EE, e = idx - bl * EE;
        elds[bl][e] = emb[(size_t)caps[bl * TT + t] * EE + e];
    }
    __syncthreads();
    float wreg[EE];
#pragma unroll
    for (int e = 0; e < EE; ++e) wreg[e] = Wih[(size_t)j * EE + e];
    float bias = bih[j] + bhh[j];
    for (int bl = 0; bl < BB; ++bl) {
        float acc = bias;
#pragma unroll
        for (int e = 0; e < EE; ++e) acc += wreg[e] * elds[bl][e];
        xw[((size_t)(t * BB + bl)) * (4 * HH) + j] = acc;
    }
}

// ---------------------------------------------------------------------------
// Init: states in [b][k] layout. fp32 masters for c/hg, bf16 copies for MFMA.
// ---------------------------------------------------------------------------
__global__ void init_state_kernel(const float* __restrict__ feat,
                                  float* __restrict__ c32, float* __restrict__ hg32,
                                  unsigned short* __restrict__ hbf,
                                  unsigned short* __restrict__ cbf,
                                  unsigned short* __restrict__ hgbf) {
    int i = blockIdx.x * 256 + threadIdx.x;    // 65536 threads
    float v = feat[i];
    c32[i] = v; hg32[i] = v;
    unsigned short b = f2bf(v);
    hbf[i] = b; cbf[i] = b; hgbf[i] = b;
}

// ---------------------------------------------------------------------------
// Persistent recurrence kernel (cooperative launch, 256 blocks x 1024 thr).
// Per step:
//   stage1: blocks [0,128): LSTM kk-strip (wave w: gate w>>2, K-quarter w&3),
//           fused LSTM activation epilogue -> c32, cbf, hout.
//           blocks [128,224): GRU gh 64-row slab -> gh (raw + bhh).
//   grid.sync()
//   stage2: blocks [0,128): GRU gi kk-strip (12 waves: gate w>>2, quarter w&3),
//           fused GRU epilogue -> hg32, hgbf, hg_all[t].
//   grid.sync()
// MFMA fragment layouts identical to the round-2/3 passing kernels.
// c32/hg32/cbf/hgbf strips are owner-stable per block across steps.
// ---------------------------------------------------------------------------
struct PKArgs {
    const unsigned short* Whh;     // [8192][2048] bf16
    const unsigned short* gWhh;    // [6144][2048] bf16
    const unsigned short* gWih;    // [6144][2048] bf16
    const float* gbhh;             // [6144]
    const float* gbih;             // [6144]
    const float* xw;               // [TS][32][8192]
    float* c32;                    // [32][2048]
    float* hg32;                   // [32][2048]
    float* gh;                     // [32][6144]
    unsigned short* hbf0;          // [32][2048]
    unsigned short* hbf1;
    unsigned short* cbf;
    unsigned short* hgbf;
    unsigned short* hg_all;        // [TS*32(+pad)][2048]
};

__global__ __launch_bounds__(1024, 4) void persistent_step_kernel(PKArgs p) {
    cg::grid_group grid = cg::this_grid();
    __shared__ float lsum[4][4][32][17];
    const int tid = threadIdx.x;
    const int lane = tid & 63;
    const int w = tid >> 6;        // 0..15
    const int l15 = lane & 15;
    const int lq = lane >> 4;      // 0..3
    const int bx = blockIdx.x;

    const int g = w >> 2;          // stage1: gate/strip; stage2: gate (w<12)
    const int kh = w & 3;          // K quarter
    const int kofs = kh * 512 + lq * 8;

    // stage1 weight row pointer (loop-invariant)
    const unsigned short* Brow1 = nullptr;
    if (bx < 128) {
        Brow1 = p.Whh + (size_t)(g * HH + bx * 16 + l15) * HH + kofs;
    } else if (bx < 224) {
        Brow1 = p.gWhh + (size_t)((bx - 128) * 64 + g * 16 + l15) * HH + kofs;
    }
    // stage2 weight row pointer (blocks < 128, waves < 12)
    const unsigned short* Brow2 = nullptr;
    if (bx < 128 && w < 12) {
        Brow2 = p.gWih + (size_t)(g * HH + bx * 16 + l15) * HH + kofs;
    }

    for (int t = 0; t < TS; ++t) {
        const unsigned short* hin  = (t & 1) ? p.hbf1 : p.hbf0;
        unsigned short*       hout = (t & 1) ? p.hbf0 : p.hbf1;
        const float* xw_t = p.xw + (size_t)t * BB * 4 * HH;

        // ---------------- stage1 MFMA ----------------
        if (bx < 224) {
            const unsigned short* Abase = (bx < 128) ? hin : p.hgbf;
            const unsigned short* Arow0 = Abase + l15 * HH + kofs;
            const unsigned short* Arow1 = Arow0 + 16 * HH;
            f32x4 acc0 = {0.f, 0.f, 0.f, 0.f};
            f32x4 acc1 = {0.f, 0.f, 0.f, 0.f};
#pragma unroll 4
            for (int it = 0; it < 16; ++it) {
                s16x8 bv = *(const s16x8*)(Brow1 + it * 32);
                s16x8 a0 = *(const s16x8*)(Arow0 + it * 32);
                s16x8 a1 = *(const s16x8*)(Arow1 + it * 32);
                acc0 = __builtin_amdgcn_mfma_f32_16x16x32_bf16(a0, bv, acc0, 0, 0, 0);
                acc1 = __builtin_amdgcn_mfma_f32_16x16x32_bf16(a1, bv, acc1, 0, 0, 0);
            }
#pragma unroll
            for (int r = 0; r < 4; ++r) {
                lsum[g][kh][lq * 4 + r][l15]      = acc0[r];
                lsum[g][kh][16 + lq * 4 + r][l15] = acc1[r];
            }
        }
        __syncthreads();

        // ---------------- stage1 epilogue ----------------
        if (bx < 128) {
            if (tid < 512) {
                int kk0 = bx * 16;
                int kkl = tid & 15, b = tid >> 4;          // 512 = 32b x 16kk
                int kk = kk0 + kkl;
                const float* xwb = xw_t + (size_t)b * 4 * HH;
                float vi = lsum[0][0][b][kkl] + lsum[0][1][b][kkl] + lsum[0][2][b][kkl] + lsum[0][3][b][kkl] + xwb[kk];
                float vf = lsum[1][0][b][kkl] + lsum[1][1][b][kkl] + lsum[1][2][b][kkl] + lsum[1][3][b][kkl] + xwb[HH + kk];
                float vg = lsum[2][0][b][kkl] + lsum[2][1][b][kkl] + lsum[2][2][b][kkl] + lsum[2][3][b][kkl] + xwb[2 * HH + kk];
                float vo = lsum[3][0][b][kkl] + lsum[3][1][b][kkl] + lsum[3][2][b][kkl] + lsum[3][3][b][kkl] + xwb[3 * HH + kk];
                int idx = b * HH + kk;
                float c = sigmf(vf) * p.c32[idx] + sigmf(vi) * tanhf_fast(vg);
                float h = sigmf(vo) * tanhf_fast(c);
                p.c32[idx] = c;
                p.cbf[idx] = f2bf(c);
                hout[idx] = f2bf(h);
            }
        } else if (bx < 224) {
            int n0 = (bx - 128) * 64;
            for (int cell = tid; cell < 2048; cell += 1024) {
                int nl = cell & 63, b = cell >> 6;
                int s = nl >> 4, n15 = nl & 15;
                float v = lsum[s][0][b][n15] + lsum[s][1][b][n15] + lsum[s][2][b][n15] + lsum[s][3][b][n15]
                          + p.gbhh[n0 + nl];
                p.gh[b * 3 * HH + n0 + nl] = v;
            }
        }
        grid.sync();

        // ---------------- stage2 MFMA (gi = cbf @ gWih.T) ----------------
        if (bx < 128 && w < 12) {
            const unsigned short* Arow0 = p.cbf + l15 * HH + kofs;
            const unsigned short* Arow1 = Arow0 + 16 * HH;
            f32x4 acc0 = {0.f, 0.f, 0.f, 0.f};
            f32x4 acc1 = {0.f, 0.f, 0.f, 0.f};
#pragma unroll 4
            for (int it = 0; it < 16; ++it) {
                s16x8 bv = *(const s16x8*)(Brow2 + it * 32);
                s16x8 a0 = *(const s16x8*)(Arow0 + it * 32);
                s16x8 a1 = *(const s16x8*)(Arow1 + it * 32);
                acc0 = __builtin_amdgcn_mfma_f32_16x16x32_bf16(a0, bv, acc0, 0, 0, 0);
                acc1 = __builtin_amdgcn_mfma_f32_16x16x32_bf16(a1, bv, acc1, 0, 0, 0);
            }
#pragma unroll
            for (int r = 0; r < 4; ++r) {
                lsum[g][kh][lq * 4 + r][l15]      = acc0[r];
                lsum[g][kh][16 + lq * 4 + r][l15] = acc1[r];
            }
        }
        __syncthreads();

        // ---------------- stage2 epilogue ----------------
        if (bx < 128 && tid < 512) {
            int kk0 = bx * 16;
            int kkl = tid & 15, b = tid >> 4;
            int kk = kk0 + kkl;
            float ri = lsum[0][0][b][kkl] + lsum[0][1][b][kkl] + lsum[0][2][b][kkl] + lsum[0][3][b][kkl] + p.gbih[kk];
            float zi = lsum[1][0][b][kkl] + lsum[1][1][b][kkl] + lsum[1][2][b][kkl] + lsum[1][3][b][kkl] + p.gbih[HH + kk];
            float ni = lsum[2][0][b][kkl] + lsum[2][1][b][kkl] + lsum[2][2][b][kkl] + lsum[2][3][b][kkl] + p.gbih[2 * HH + kk];
            const float* ghb = p.gh + b * 3 * HH;
            float r = sigmf(ri + ghb[kk]);
            float z = sigmf(zi + ghb[HH + kk]);
            float n = tanhf_fast(ni + r * ghb[2 * HH + kk]);
            int idx = b * HH + kk;
            float hgn = (1.f - z) * n + z * p.hg32[idx];
            p.hg32[idx] = hgn;
            unsigned short hb = f2bf(hgn);
            p.hgbf[idx] = hb;
            p.hg_all[(size_t)t * BB * HH + idx] = hb;
        }
        grid.sync();
    }
}

// ---------------------------------------------------------------------------
// Phase C: out = hg_all @ linW.T + b. bf16 MFMA, 128x128 tile, BK=32.
// ---------------------------------------------------------------------------
__global__ __launch_bounds__(256) void out_gemm_kernel(
    const unsigned short* __restrict__ A,     // [1280][2048] (rows >=1248 junk)
    const unsigned short* __restrict__ Wl,    // [8000][2048] (reads to 8063 ok)
    const float* __restrict__ bl,
    float* __restrict__ out) {
    __shared__ unsigned short As[128][32];
    __shared__ unsigned short Bs[128][32];
    const int tid = threadIdx.x;
    const int lane = tid & 63;
    const int w = tid >> 6;
    const int l15 = lane & 15;
    const int lq = lane >> 4;
    const int mt = blockIdx.x, nt = blockIdx.y;
    const int mq = w >> 1, nq = w & 1;

    const int row0 = tid >> 2, kc0 = (tid & 3) * 8;
    const unsigned short* Ap0 = A + (size_t)(mt * 128 + row0) * HH + kc0;
    const unsigned short* Ap1 = A + (size_t)(mt * 128 + 64 + row0) * HH + kc0;
    const unsigned short* Bp0 = Wl + (size_t)(nt * 128 + row0) * HH + kc0;
    const unsigned short* Bp1 = Wl + (size_t)(nt * 128 + 64 + row0) * HH + kc0;

    f32x4 acc[4][4];
#pragma unroll
    for (int i = 0; i < 4; ++i)
#pragma unroll
        for (int j = 0; j < 4; ++j) acc[i][j] = (f32x4){0.f, 0.f, 0.f, 0.f};

    for (int k0 = 0; k0 < HH; k0 += 32) {
        s16x8 a0v = *(const s16x8*)(Ap0 + k0);
        s16x8 a1v = *(const s16x8*)(Ap1 + k0);
        s16x8 b0v = *(const s16x8*)(Bp0 + k0);
        s16x8 b1v = *(const s16x8*)(Bp1 + k0);
        *(s16x8*)&As[row0][kc0]      = a0v;
        *(s16x8*)&As[64 + row0][kc0] = a1v;
        *(s16x8*)&Bs[row0][kc0]      = b0v;
        *(s16x8*)&Bs[64 + row0][kc0] = b1v;
        __syncthreads();
        s16x8 af[4], bf[4];
#pragma unroll
        for (int i = 0; i < 4; ++i) af[i] = *(const s16x8*)&As[mq * 64 + i * 16 + l15][lq * 8];
#pragma unroll
        for (int j = 0; j < 4; ++j) bf[j] = *(const s16x8*)&Bs[nq * 64 + j * 16 + l15][lq * 8];
#pragma unroll
        for (int i = 0; i < 4; ++i)
#pragma unroll
            for (int j = 0; j < 4; ++j)
                acc[i][j] = __builtin_amdgcn_mfma_f32_16x16x32_bf16(af[i], bf[j], acc[i][j], 0, 0, 0);
        __syncthreads();
    }
#pragma unroll
    for (int j = 0; j < 4; ++j) {
        int n = nt * 128 + nq * 64 + j * 16 + l15;
        float bn = bl[n < VV ? n : VV - 1];
#pragma unroll
        for (int i = 0; i < 4; ++i) {
#pragma unroll
            for (int r = 0; r < 4; ++r) {
                int m = mt * 128 + mq * 64 + i * 16 + lq * 4 + r;
                if (m < TS * BB && n < VV) {
                    int t = m >> 5, b = m & 31;
                    out[((size_t)b * TS + t) * VV + n] = acc[i][j][r] + bn;
                }
            }
        }
    }
}

// ---------------------------------------------------------------------------
extern "C" void kernel_launch(void* const* d_in, const int* in_sizes, int n_in,
                              void* d_out, int out_size, void* d_ws, size_t ws_size,
                              hipStream_t stream) {
    const float* features = (const float*)d_in[0];
    const int*   captions = (const int*)d_in[1];
    const float* emb      = (const float*)d_in[2];
    const float* lstm_Wih = (const float*)d_in[3];
    const float* lstm_bih = (const float*)d_in[4];
    const float* lstm_Whh = (const float*)d_in[5];
    const float* lstm_bhh = (const float*)d_in[6];
    const float* gru_Wih  = (const float*)d_in[7];
    const float* gru_bih  = (const float*)d_in[8];
    const float* gru_Whh  = (const float*)d_in[9];
    const float* gru_bhh  = (const float*)d_in[10];
    const float* lin_W    = (const float*)d_in[11];
    const float* lin_b    = (const float*)d_in[12];
    float* out = (float*)d_out;

    // workspace layout (bf16 section first, then fp32) — ~165 MB total
    unsigned short* us = (unsigned short*)d_ws;
    unsigned short* Whh_bf  = us;                              // 8192*2048
    unsigned short* gWhh_bf = Whh_bf  + (size_t)8192 * HH;     // 6144*2048
    unsigned short* gWih_bf = gWhh_bf + (size_t)6144 * HH;     // 6144*2048
    unsigned short* linW_bf = gWih_bf + (size_t)6144 * HH;     // 8000*2048
    unsigned short* hbf0    = linW_bf + (size_t)VV * HH;
    unsigned short* hbf1    = hbf0 + BB * HH;
    unsigned short* cbf     = hbf1 + BB * HH;
    unsigned short* hgbf    = cbf  + BB * HH;
    unsigned short* hg_all  = hgbf + BB * HH;                  // 1280*2048 (padded)
    float* f32s = (float*)(hg_all + (size_t)1280 * HH);
    float* xw   = f32s;                                        // 39*32*8192
    float* c32  = xw + (size_t)TS * BB * 4 * HH;
    float* hg32 = c32 + BB * HH;
    float* gh   = hg32 + BB * HH;                              // 32*6144

    // 1) weight conversion (d_ws is re-poisoned before every call)
    {
        int n4;
        n4 = 8192 * HH / 4;
        convert_kernel<<<(n4 + 255) / 256, 256, 0, stream>>>(lstm_Whh, Whh_bf, n4);
        n4 = 6144 * HH / 4;
        convert_kernel<<<(n4 + 255) / 256, 256, 0, stream>>>(gru_Whh, gWhh_bf, n4);
        convert_kernel<<<(n4 + 255) / 256, 256, 0, stream>>>(gru_Wih, gWih_bf, n4);
        n4 = VV * HH / 4;
        convert_kernel<<<(n4 + 255) / 256, 256, 0, stream>>>(lin_W, linW_bf, n4);
    }

    // 2) precompute x-side gate biases for all steps
    embed_proj_kernel<<<dim3(4 * HH / 256, TS), 256, 0, stream>>>(
        captions, emb, lstm_Wih, lstm_bih, lstm_bhh, xw);

    // 3) init states
    init_state_kernel<<<(BB * HH) / 256, 256, 0, stream>>>(
        features, c32, hg32, hbf0, cbf, hgbf);

    // 4) recurrence: single persistent cooperative kernel
    {
        PKArgs pk;
        pk.Whh = Whh_bf; pk.gWhh = gWhh_bf; pk.gWih = gWih_bf;
        pk.gbhh = gru_bhh; pk.gbih = gru_bih;
        pk.xw = xw;
        pk.c32 = c32; pk.hg32 = hg32; pk.gh = gh;
        pk.hbf0 = hbf0; pk.hbf1 = hbf1; pk.cbf = cbf; pk.hgbf = hgbf;
        pk.hg_all = hg_all;
        void* kargs[] = { (void*)&pk };
        hipLaunchCooperativeKernel((const void*)persistent_step_kernel,
                                   dim3(256), dim3(1024), kargs, 0, stream);
    }

    // 5) output projection
    out_gemm_kernel<<<dim3((TS * BB + 127) / 128, (VV + 127) / 128), 256, 0, stream>>>(
        hg_all, linW_bf, lin_b, out);
}